// Round 1
// baseline (8434.860 us; speedup 1.0000x reference)
//
#include <hip/hip_runtime.h>
#include <math.h>

namespace {
constexpr int B_   = 2;
constexpr int C_   = 256;
constexpr int NH_  = 8;
constexpr int DH_  = 32;
constexpr int NP_  = 4;
constexpr int DFF_ = 1024;
constexpr int LQ_  = 21760;
constexpr int M_   = B_ * LQ_;   // 43520
}

// ---------------- assemble: src/pos [B,C,H,W] -> [B,LQ,C]; pos += level_embed ----
__global__ void k_assemble(const float* __restrict__ s0, const float* __restrict__ s1,
                           const float* __restrict__ s2, const float* __restrict__ s3,
                           const float* __restrict__ p0, const float* __restrict__ p1,
                           const float* __restrict__ p2, const float* __restrict__ p3,
                           const float* __restrict__ lev,
                           float* __restrict__ xout, float* __restrict__ posout)
{
    int i = blockIdx.x * blockDim.x + threadIdx.x;
    if (i >= B_ * LQ_ * C_) return;
    int c = i & (C_ - 1);
    int s = (i / C_) % LQ_;
    int b = i / (C_ * LQ_);
    const float *sp, *pp;
    int lv, off, HW;
    if (s < 16384)      { lv = 0; off = s;         HW = 16384; sp = s0; pp = p0; }
    else if (s < 20480) { lv = 1; off = s - 16384; HW = 4096;  sp = s1; pp = p1; }
    else if (s < 21504) { lv = 2; off = s - 20480; HW = 1024;  sp = s2; pp = p2; }
    else                { lv = 3; off = s - 21504; HW = 256;   sp = s3; pp = p3; }
    size_t si = ((size_t)(b * C_ + c)) * HW + off;
    xout[i]   = sp[si];
    posout[i] = pp[si] + lev[lv * C_ + c];
}

// ---------------- q = x + pos (float4) ----------------
__global__ void k_add4(const float4* __restrict__ a, const float4* __restrict__ b,
                       float4* __restrict__ o, int n4)
{
    int i = blockIdx.x * blockDim.x + threadIdx.x;
    if (i < n4) {
        float4 va = a[i], vb = b[i];
        o[i] = make_float4(va.x + vb.x, va.y + vb.y, va.z + vb.z, va.w + vb.w);
    }
}

// ---------------- fp32 tiled GEMM: C = A[M,K] * B[K,N] + bias, optional relu ----
template<bool RELU>
__global__ __launch_bounds__(256) void k_gemm(const float* __restrict__ A,
                                              const float* __restrict__ Bw,
                                              const float* __restrict__ bias,
                                              float* __restrict__ Co,
                                              int M, int N, int K)
{
    constexpr int BM = 64, BN = 64, BK = 16;
    __shared__ float As[BK][BM + 4];
    __shared__ float Bs[BK][BN + 4];
    int t  = threadIdx.x;
    int tx = t & 15, ty = t >> 4;
    int m0 = blockIdx.x * BM;
    int n0 = blockIdx.y * BN;
    float acc[4][4] = {};

    for (int k0 = 0; k0 < K; k0 += BK) {
        {
            int kk = t & 15, rr = t >> 4;
#pragma unroll
            for (int p = 0; p < 4; p++) {
                int row = rr + p * 16;
                As[kk][row] = A[(size_t)(m0 + row) * K + k0 + kk];
            }
            int nn = t & 63, kr = t >> 6;
#pragma unroll
            for (int p = 0; p < 4; p++) {
                int k = kr + p * 4;
                Bs[k][nn] = Bw[(size_t)(k0 + k) * N + n0 + nn];
            }
        }
        __syncthreads();
#pragma unroll
        for (int k = 0; k < BK; k++) {
            float4 av = *(const float4*)&As[k][ty * 4];
            float4 bv = *(const float4*)&Bs[k][tx * 4];
            float a[4] = {av.x, av.y, av.z, av.w};
            float b[4] = {bv.x, bv.y, bv.z, bv.w};
#pragma unroll
            for (int i = 0; i < 4; i++)
#pragma unroll
                for (int j = 0; j < 4; j++)
                    acc[i][j] = fmaf(a[i], b[j], acc[i][j]);
        }
        __syncthreads();
    }

    float4 bv = *(const float4*)&bias[n0 + tx * 4];
    float bb[4] = {bv.x, bv.y, bv.z, bv.w};
#pragma unroll
    for (int i = 0; i < 4; i++) {
        int m = m0 + ty * 4 + i;
        float4 o;
        float* op = &o.x;
#pragma unroll
        for (int j = 0; j < 4; j++) {
            float v = acc[i][j] + bb[j];
            if (RELU) v = fmaxf(v, 0.f);
            op[j] = v;
        }
        *(float4*)&Co[(size_t)m * N + n0 + tx * 4] = o;
    }
}

// ---------------- softmax over 16 (per b,s,h row) ----------------
__global__ void k_softmax16(float* __restrict__ a, int nrows)
{
    int r = blockIdx.x * blockDim.x + threadIdx.x;
    if (r >= nrows) return;
    float* p = a + (size_t)r * 16;
    float v[16];
    float4* vp = (float4*)v;
    const float4* pr = (const float4*)p;
#pragma unroll
    for (int i = 0; i < 4; i++) vp[i] = pr[i];
    float mx = v[0];
#pragma unroll
    for (int i = 1; i < 16; i++) mx = fmaxf(mx, v[i]);
    float s = 0.f;
#pragma unroll
    for (int i = 0; i < 16; i++) { v[i] = expf(v[i] - mx); s += v[i]; }
    float inv = 1.f / s;
#pragma unroll
    for (int i = 0; i < 16; i++) v[i] *= inv;
    float4* pw = (float4*)p;
#pragma unroll
    for (int i = 0; i < 4; i++) pw[i] = vp[i];
}

// ---------------- deformable sampling ----------------
// block = 256 threads = (h = t>>5, d = t&31), one block per (b,s)
__global__ __launch_bounds__(256) void k_sample(const float* __restrict__ val,
                                                const float* __restrict__ off,
                                                const float* __restrict__ attn,
                                                float* __restrict__ out)
{
    int bs = blockIdx.x;           // 0..M_-1
    int b  = bs / LQ_;
    int s  = bs % LQ_;
    __shared__ float offs[256];
    __shared__ float atts[128];
    int t = threadIdx.x;
    offs[t] = off[(size_t)bs * 256 + t];
    if (t < 128) atts[t] = attn[(size_t)bs * 128 + t];
    __syncthreads();

    int h = t >> 5, d = t & 31;
    int p0_, Hq, Wq;
    if (s < 16384)      { p0_ = s;         Hq = 128; Wq = 128; }
    else if (s < 20480) { p0_ = s - 16384; Hq = 64;  Wq = 64;  }
    else if (s < 21504) { p0_ = s - 20480; Hq = 32;  Wq = 32;  }
    else                { p0_ = s - 21504; Hq = 16;  Wq = 16;  }
    int iy = p0_ / Wq, ix = p0_ % Wq;
    float refx = (ix + 0.5f) / Wq;
    float refy = (iy + 0.5f) / Hq;

    const int HH[4] = {128, 64, 32, 16};
    const int S0[4] = {0, 16384, 20480, 21504};
    float acc = 0.f;
#pragma unroll
    for (int lv = 0; lv < 4; lv++) {
        int Hl = HH[lv], Wl = HH[lv];
        float fW = (float)Wl, fH = (float)Hl;
        const float* vb = val + ((size_t)b * LQ_ + S0[lv]) * C_ + h * DH_ + d;
#pragma unroll
        for (int p = 0; p < NP_; p++) {
            float ox = offs[((h * 4 + lv) * 4 + p) * 2 + 0];
            float oy = offs[((h * 4 + lv) * 4 + p) * 2 + 1];
            float aw = atts[h * 16 + lv * 4 + p];
            float lx = refx + ox / fW;
            float ly = refy + oy / fH;
            float xx = lx * fW - 0.5f;
            float yy = ly * fH - 0.5f;
            float x0f = floorf(xx), y0f = floorf(yy);
            float wx = xx - x0f, wy = yy - y0f;
            int x0 = (int)x0f, y0 = (int)y0f;
            int x1 = x0 + 1, y1 = y0 + 1;
            bool vx0 = (x0 >= 0) & (x0 < Wl), vx1 = (x1 >= 0) & (x1 < Wl);
            bool vy0 = (y0 >= 0) & (y0 < Hl), vy1 = (y1 >= 0) & (y1 < Hl);
            int cx0 = min(max(x0, 0), Wl - 1), cx1 = min(max(x1, 0), Wl - 1);
            int cy0 = min(max(y0, 0), Hl - 1), cy1 = min(max(y1, 0), Hl - 1);
            float g00 = vb[(size_t)(cy0 * Wl + cx0) * C_];
            float g10 = vb[(size_t)(cy0 * Wl + cx1) * C_];
            float g01 = vb[(size_t)(cy1 * Wl + cx0) * C_];
            float g11 = vb[(size_t)(cy1 * Wl + cx1) * C_];
            float w00 = (1.f - wx) * (1.f - wy) * ((vx0 & vy0) ? 1.f : 0.f);
            float w10 = wx * (1.f - wy) * ((vx1 & vy0) ? 1.f : 0.f);
            float w01 = (1.f - wx) * wy * ((vx0 & vy1) ? 1.f : 0.f);
            float w11 = wx * wy * ((vx1 & vy1) ? 1.f : 0.f);
            acc += aw * (w00 * g00 + w10 * g10 + w01 * g01 + w11 * g11);
        }
    }
    out[(size_t)bs * C_ + t] = acc;
}

// ---------------- x = LN(x + res) * g + b (row = 256) ----------------
__global__ __launch_bounds__(256) void k_addln(float* __restrict__ x,
                                               const float* __restrict__ res,
                                               const float* __restrict__ g,
                                               const float* __restrict__ bta)
{
    int r = blockIdx.x;
    int t = threadIdx.x;
    size_t idx = (size_t)r * C_ + t;
    float v = x[idx] + res[idx];

    __shared__ float red[4];
    int lane = t & 63, wid = t >> 6;

    float s = v;
#pragma unroll
    for (int o = 32; o > 0; o >>= 1) s += __shfl_down(s, o);
    if (lane == 0) red[wid] = s;
    __syncthreads();
    float mu = (red[0] + red[1] + red[2] + red[3]) * (1.f / C_);
    __syncthreads();

    float dv = v - mu;
    float s2 = dv * dv;
#pragma unroll
    for (int o = 32; o > 0; o >>= 1) s2 += __shfl_down(s2, o);
    if (lane == 0) red[wid] = s2;
    __syncthreads();
    float var = (red[0] + red[1] + red[2] + red[3]) * (1.f / C_);

    x[idx] = dv * rsqrtf(var + 1e-5f) * g[t] + bta[t];
}

// ---------------- driver ----------------
extern "C" void kernel_launch(void* const* d_in, const int* in_sizes, int n_in,
                              void* d_out, int out_size, void* d_ws, size_t ws_size,
                              hipStream_t stream)
{
    // setup_inputs dict order: src0,pos0,src1,pos1,src2,pos2,src3,pos3,level_embed,
    // Woff,boff,Wattn,battn,Wval,bval,Wout,bout,g1,b1,Wff1,bff1,Wff2,bff2,g2,b2
    const float* src_[4] = {(const float*)d_in[0], (const float*)d_in[2],
                            (const float*)d_in[4], (const float*)d_in[6]};
    const float* pos_[4] = {(const float*)d_in[1], (const float*)d_in[3],
                            (const float*)d_in[5], (const float*)d_in[7]};
    const float* lev   = (const float*)d_in[8];
    const float* Woff  = (const float*)d_in[9];
    const float* boff  = (const float*)d_in[10];
    const float* Wattn = (const float*)d_in[11];
    const float* battn = (const float*)d_in[12];
    const float* Wval  = (const float*)d_in[13];
    const float* bval  = (const float*)d_in[14];
    const float* Wout  = (const float*)d_in[15];
    const float* bout  = (const float*)d_in[16];
    const float* g1    = (const float*)d_in[17];
    const float* b1    = (const float*)d_in[18];
    const float* Wff1  = (const float*)d_in[19];
    const float* bff1  = (const float*)d_in[20];
    const float* Wff2  = (const float*)d_in[21];
    const float* bff2  = (const float*)d_in[22];
    const float* g2    = (const float*)d_in[23];
    const float* b2    = (const float*)d_in[24];

    float* x  = (float*)d_out;            // persistent hidden state
    float* ws = (float*)d_ws;
    size_t MC = (size_t)M_ * C_;
    float* posb = ws;              ws += MC;
    float* qb   = ws;              ws += MC;   // q, later sampled
    float* offb = ws;              ws += MC;   // off, later out2 / fftmp
    float* valb = ws;              ws += MC;   // val, later ff hidden chunks
    float* attb = ws;              ws += (size_t)M_ * 128;

    int nElem = M_ * C_;
    int n4    = nElem / 4;
    dim3 blk(256);

    k_assemble<<<(nElem + 255) / 256, blk, 0, stream>>>(
        src_[0], src_[1], src_[2], src_[3],
        pos_[0], pos_[1], pos_[2], pos_[3], lev, x, posb);

    constexpr int Mc = M_ / 4;   // 10880, FF chunk rows

    for (int l = 0; l < 6; l++) {
        // q = x + pos
        k_add4<<<(n4 + 255) / 256, blk, 0, stream>>>(
            (const float4*)x, (const float4*)posb, (float4*)qb, n4);

        // off = q @ Woff + boff   [M,256]
        k_gemm<false><<<dim3(M_ / 64, 256 / 64), blk, 0, stream>>>(
            qb, Woff + (size_t)l * C_ * 256, boff + l * 256, offb, M_, 256, C_);

        // attn logits = q @ Wattn + battn  [M,128]
        k_gemm<false><<<dim3(M_ / 64, 128 / 64), blk, 0, stream>>>(
            qb, Wattn + (size_t)l * C_ * 128, battn + l * 128, attb, M_, 128, C_);

        k_softmax16<<<(M_ * NH_ + 255) / 256, blk, 0, stream>>>(attb, M_ * NH_);

        // val = x @ Wval + bval  [M,256]
        k_gemm<false><<<dim3(M_ / 64, 256 / 64), blk, 0, stream>>>(
            x, Wval + (size_t)l * C_ * 256, bval + l * 256, valb, M_, 256, C_);

        // deformable sampling -> qb (q no longer needed)
        k_sample<<<M_, blk, 0, stream>>>(valb, offb, attb, qb);

        // out2 = sampled @ Wout + bout -> offb
        k_gemm<false><<<dim3(M_ / 64, 256 / 64), blk, 0, stream>>>(
            qb, Wout + (size_t)l * C_ * 256, bout + l * 256, offb, M_, 256, C_);

        // x = LN(x + out2)
        k_addln<<<M_, blk, 0, stream>>>(x, offb, g1 + l * 256, b1 + l * 256);

        // FF in 4 chunks: h1 = relu(x @ Wff1 + bff1); fftmp = h1 @ Wff2 + bff2
        for (int ch = 0; ch < 4; ch++) {
            const float* xa = x + (size_t)ch * Mc * C_;
            k_gemm<true><<<dim3(Mc / 64, DFF_ / 64), blk, 0, stream>>>(
                xa, Wff1 + (size_t)l * C_ * DFF_, bff1 + l * DFF_, valb, Mc, DFF_, C_);
            k_gemm<false><<<dim3(Mc / 64, 256 / 64), blk, 0, stream>>>(
                valb, Wff2 + (size_t)l * DFF_ * C_, bff2 + l * C_,
                offb + (size_t)ch * Mc * C_, Mc, 256, DFF_);
        }

        // x = LN(x + ff)
        k_addln<<<M_, blk, 0, stream>>>(x, offb, g2 + l * 256, b2 + l * 256);
    }
}

// Round 2
// 3913.646 us; speedup vs baseline: 2.1552x; 2.1552x over previous
//
#include <hip/hip_runtime.h>
#include <hip/hip_bf16.h>
#include <math.h>

namespace {
constexpr int B_   = 2;
constexpr int C_   = 256;
constexpr int NH_  = 8;
constexpr int DH_  = 32;
constexpr int NP_  = 4;
constexpr int DFF_ = 1024;
constexpr int LQ_  = 21760;
constexpr int M_   = B_ * LQ_;     // 43520
constexpr int Mc_  = M_ / 4;       // 10880 FF chunk rows
}

typedef __bf16  bf16x8 __attribute__((ext_vector_type(8)));
typedef short   s16x8  __attribute__((ext_vector_type(8)));
typedef unsigned short u16x8 __attribute__((ext_vector_type(8)));
typedef float   f32x4  __attribute__((ext_vector_type(4)));

static __device__ __forceinline__ unsigned short f2bf(float f) {
    return __builtin_bit_cast(unsigned short, __float2bfloat16(f));
}
static __device__ __forceinline__ float bf2f(unsigned short u) {
    return __bfloat162float(__builtin_bit_cast(__hip_bfloat16, u));
}

// ---------- weight transpose + cvt: in [L][K][N] f32 -> out [L][N][K] bf16 ----------
__global__ void k_wt(const float* __restrict__ in, __hip_bfloat16* __restrict__ out,
                     int K, int N)
{
    __shared__ float tile[32][33];
    int n0 = blockIdx.x * 32, k0 = blockIdx.y * 32;
    const float* inl = in + (size_t)blockIdx.z * K * N;
    __hip_bfloat16* outl = out + (size_t)blockIdx.z * K * N;
    for (int i = threadIdx.y; i < 32; i += 8)
        tile[i][threadIdx.x] = inl[(size_t)(k0 + i) * N + n0 + threadIdx.x];
    __syncthreads();
    for (int i = threadIdx.y; i < 32; i += 8)
        outl[(size_t)(n0 + i) * K + k0 + threadIdx.x] = __float2bfloat16(tile[threadIdx.x][i]);
}

// ---------- assemble: src/pos [B,C,H,W] -> [B,LQ,C]; pos += level_embed ----------
__global__ void k_assemble(const float* __restrict__ s0, const float* __restrict__ s1,
                           const float* __restrict__ s2, const float* __restrict__ s3,
                           const float* __restrict__ p0, const float* __restrict__ p1,
                           const float* __restrict__ p2, const float* __restrict__ p3,
                           const float* __restrict__ lev,
                           float* __restrict__ xout, __hip_bfloat16* __restrict__ xbf,
                           __hip_bfloat16* __restrict__ posbf)
{
    int i = blockIdx.x * blockDim.x + threadIdx.x;
    if (i >= B_ * LQ_ * C_) return;
    int c = i & (C_ - 1);
    int s = (i / C_) % LQ_;
    int b = i / (C_ * LQ_);
    const float *sp, *pp;
    int lv, off, HW;
    if (s < 16384)      { lv = 0; off = s;         HW = 16384; sp = s0; pp = p0; }
    else if (s < 20480) { lv = 1; off = s - 16384; HW = 4096;  sp = s1; pp = p1; }
    else if (s < 21504) { lv = 2; off = s - 20480; HW = 1024;  sp = s2; pp = p2; }
    else                { lv = 3; off = s - 21504; HW = 256;   sp = s3; pp = p3; }
    size_t si = ((size_t)(b * C_ + c)) * HW + off;
    float v = sp[si];
    xout[i]  = v;
    xbf[i]   = __float2bfloat16(v);
    posbf[i] = __float2bfloat16(pp[si] + lev[lv * C_ + c]);
}

// ---------- q_bf = bf16(x + pos_bf), 8 elems/thread ----------
__global__ void k_addq(const float4* __restrict__ x, const u16x8* __restrict__ pos,
                       u16x8* __restrict__ q, int n8)
{
    int i = blockIdx.x * blockDim.x + threadIdx.x;
    if (i >= n8) return;
    float4 a = x[2 * i], b = x[2 * i + 1];
    u16x8 p = pos[i];
    float va[8] = {a.x, a.y, a.z, a.w, b.x, b.y, b.z, b.w};
    u16x8 o;
#pragma unroll
    for (int j = 0; j < 8; j++)
        o[j] = f2bf(va[j] + bf2f(p[j]));
    q[i] = o;
}

// ---------- bf16 MFMA GEMM: out = A[M,K] @ W^T[N,K]^T + bias ----------
// 128x128 tile, BK=64, 4 waves (2x2), global_load_lds w=16, XOR-swizzled LDS.
template<bool RELU, bool BF16OUT>
__global__ __launch_bounds__(256) void k_gemm_mfma(
    const __hip_bfloat16* __restrict__ A,    // [M,K]
    const __hip_bfloat16* __restrict__ Wt,   // [N,K]
    const float* __restrict__ bias,          // [N]
    void* __restrict__ Co,                   // [M,N] f32 or bf16
    int M, int N, int K)
{
    __shared__ char As[128 * 128];   // 128 rows x 128 bytes (64 bf16)
    __shared__ char Bs[128 * 128];
    int t = threadIdx.x, w = t >> 6, lane = t & 63;
    int m0 = blockIdx.x * 128, n0 = blockIdx.y * 128;
    int wm = w >> 1, wn = w & 1;

    f32x4 acc[4][4] = {};

    // staging: lane covers row rowbase+(lane>>3), bytes (lane&7)*16 within row.
    // inverse-swizzle the SOURCE column so swizzled reads see linear data.
    int rowoff  = lane >> 3;                                  // 0..7
    int colswz  = ((lane & 7) ^ (lane >> 3)) << 3;            // elements

    for (int kt = 0; kt < K; kt += 64) {
#pragma unroll
        for (int j = 0; j < 4; j++) {
            int rowbase = w * 32 + j * 8;
            const __hip_bfloat16* srcA = A  + (size_t)(m0 + rowbase + rowoff) * K + kt + colswz;
            const __hip_bfloat16* srcB = Wt + (size_t)(n0 + rowbase + rowoff) * K + kt + colswz;
            __builtin_amdgcn_global_load_lds(
                (const __attribute__((address_space(1))) void*)srcA,
                (__attribute__((address_space(3))) void*)(As + rowbase * 128), 16, 0, 0);
            __builtin_amdgcn_global_load_lds(
                (const __attribute__((address_space(1))) void*)srcB,
                (__attribute__((address_space(3))) void*)(Bs + rowbase * 128), 16, 0, 0);
        }
        __syncthreads();
#pragma unroll
        for (int k0 = 0; k0 < 64; k0 += 32) {
            int kb = k0 * 2 + (lane >> 4) * 16;   // byte offset of this lane's 8 k's
            bf16x8 af[4], bfr[4];
#pragma unroll
            for (int mi = 0; mi < 4; mi++) {
                int r = wm * 64 + mi * 16 + (lane & 15);
                s16x8 raw = *(const s16x8*)(As + r * 128 + (kb ^ ((r & 7) << 4)));
                af[mi] = __builtin_bit_cast(bf16x8, raw);
            }
#pragma unroll
            for (int ni = 0; ni < 4; ni++) {
                int r = wn * 64 + ni * 16 + (lane & 15);
                s16x8 raw = *(const s16x8*)(Bs + r * 128 + (kb ^ ((r & 7) << 4)));
                bfr[ni] = __builtin_bit_cast(bf16x8, raw);
            }
#pragma unroll
            for (int mi = 0; mi < 4; mi++)
#pragma unroll
                for (int ni = 0; ni < 4; ni++)
                    acc[mi][ni] = __builtin_amdgcn_mfma_f32_16x16x32_bf16(
                        af[mi], bfr[ni], acc[mi][ni], 0, 0, 0);
        }
        __syncthreads();
    }

    // epilogue: C/D layout col=lane&15, row=(lane>>4)*4+reg
#pragma unroll
    for (int ni = 0; ni < 4; ni++) {
        int col = n0 + wn * 64 + ni * 16 + (lane & 15);
        float bb = bias[col];
#pragma unroll
        for (int mi = 0; mi < 4; mi++) {
            int row = m0 + wm * 64 + mi * 16 + ((lane >> 4) << 2);
#pragma unroll
            for (int r = 0; r < 4; r++) {
                float v = acc[mi][ni][r] + bb;
                if (RELU) v = fmaxf(v, 0.f);
                if (BF16OUT)
                    ((__hip_bfloat16*)Co)[(size_t)(row + r) * N + col] = __float2bfloat16(v);
                else
                    ((float*)Co)[(size_t)(row + r) * N + col] = v;
            }
        }
    }
}

// ---------- softmax over 16 (per b,s,h row) ----------
__global__ void k_softmax16(float* __restrict__ a, int nrows)
{
    int r = blockIdx.x * blockDim.x + threadIdx.x;
    if (r >= nrows) return;
    float* p = a + (size_t)r * 16;
    float v[16];
    float4* vp = (float4*)v;
    const float4* pr = (const float4*)p;
#pragma unroll
    for (int i = 0; i < 4; i++) vp[i] = pr[i];
    float mx = v[0];
#pragma unroll
    for (int i = 1; i < 16; i++) mx = fmaxf(mx, v[i]);
    float s = 0.f;
#pragma unroll
    for (int i = 0; i < 16; i++) { v[i] = expf(v[i] - mx); s += v[i]; }
    float inv = 1.f / s;
#pragma unroll
    for (int i = 0; i < 16; i++) v[i] *= inv;
    float4* pw = (float4*)p;
#pragma unroll
    for (int i = 0; i < 4; i++) pw[i] = vp[i];
}

// ---------- deformable sampling (bf16 val, bf16 out) ----------
__global__ __launch_bounds__(256) void k_sample(const __hip_bfloat16* __restrict__ val,
                                                const float* __restrict__ off,
                                                const float* __restrict__ attn,
                                                __hip_bfloat16* __restrict__ out)
{
    int bs = blockIdx.x;
    int b  = bs / LQ_;
    int s  = bs % LQ_;
    __shared__ float offs[256];
    __shared__ float atts[128];
    int t = threadIdx.x;
    offs[t] = off[(size_t)bs * 256 + t];
    if (t < 128) atts[t] = attn[(size_t)bs * 128 + t];
    __syncthreads();

    int h = t >> 5, d = t & 31;
    int p0_, Hq, Wq;
    if (s < 16384)      { p0_ = s;         Hq = 128; Wq = 128; }
    else if (s < 20480) { p0_ = s - 16384; Hq = 64;  Wq = 64;  }
    else if (s < 21504) { p0_ = s - 20480; Hq = 32;  Wq = 32;  }
    else                { p0_ = s - 21504; Hq = 16;  Wq = 16;  }
    int iy = p0_ / Wq, ix = p0_ % Wq;
    float refx = (ix + 0.5f) / Wq;
    float refy = (iy + 0.5f) / Hq;

    const int HH[4] = {128, 64, 32, 16};
    const int S0[4] = {0, 16384, 20480, 21504};
    float acc = 0.f;
#pragma unroll
    for (int lv = 0; lv < 4; lv++) {
        int Hl = HH[lv], Wl = HH[lv];
        float fW = (float)Wl, fH = (float)Hl;
        const __hip_bfloat16* vb = val + ((size_t)b * LQ_ + S0[lv]) * C_ + h * DH_ + d;
#pragma unroll
        for (int p = 0; p < NP_; p++) {
            float ox = offs[((h * 4 + lv) * 4 + p) * 2 + 0];
            float oy = offs[((h * 4 + lv) * 4 + p) * 2 + 1];
            float aw = atts[h * 16 + lv * 4 + p];
            float xx = (refx + ox / fW) * fW - 0.5f;
            float yy = (refy + oy / fH) * fH - 0.5f;
            float x0f = floorf(xx), y0f = floorf(yy);
            float wx = xx - x0f, wy = yy - y0f;
            int x0 = (int)x0f, y0 = (int)y0f;
            int x1 = x0 + 1, y1 = y0 + 1;
            bool vx0 = (x0 >= 0) & (x0 < Wl), vx1 = (x1 >= 0) & (x1 < Wl);
            bool vy0 = (y0 >= 0) & (y0 < Hl), vy1 = (y1 >= 0) & (y1 < Hl);
            int cx0 = min(max(x0, 0), Wl - 1), cx1 = min(max(x1, 0), Wl - 1);
            int cy0 = min(max(y0, 0), Hl - 1), cy1 = min(max(y1, 0), Hl - 1);
            float g00 = __bfloat162float(vb[(size_t)(cy0 * Wl + cx0) * C_]);
            float g10 = __bfloat162float(vb[(size_t)(cy0 * Wl + cx1) * C_]);
            float g01 = __bfloat162float(vb[(size_t)(cy1 * Wl + cx0) * C_]);
            float g11 = __bfloat162float(vb[(size_t)(cy1 * Wl + cx1) * C_]);
            float w00 = (1.f - wx) * (1.f - wy) * ((vx0 & vy0) ? 1.f : 0.f);
            float w10 = wx * (1.f - wy) * ((vx1 & vy0) ? 1.f : 0.f);
            float w01 = (1.f - wx) * wy * ((vx0 & vy1) ? 1.f : 0.f);
            float w11 = wx * wy * ((vx1 & vy1) ? 1.f : 0.f);
            acc += aw * (w00 * g00 + w10 * g10 + w01 * g01 + w11 * g11);
        }
    }
    out[(size_t)bs * C_ + t] = __float2bfloat16(acc);
}

// ---------- x = LN(x + res) * g + b; also write bf16 copy ----------
__global__ __launch_bounds__(256) void k_addln(float* __restrict__ x,
                                               const float* __restrict__ res,
                                               const float* __restrict__ g,
                                               const float* __restrict__ bta,
                                               __hip_bfloat16* __restrict__ xbf)
{
    int r = blockIdx.x;
    int t = threadIdx.x;
    size_t idx = (size_t)r * C_ + t;
    float v = x[idx] + res[idx];

    __shared__ float red[4];
    int lane = t & 63, wid = t >> 6;

    float s = v;
#pragma unroll
    for (int o = 32; o > 0; o >>= 1) s += __shfl_down(s, o);
    if (lane == 0) red[wid] = s;
    __syncthreads();
    float mu = (red[0] + red[1] + red[2] + red[3]) * (1.f / C_);
    __syncthreads();

    float dv = v - mu;
    float s2 = dv * dv;
#pragma unroll
    for (int o = 32; o > 0; o >>= 1) s2 += __shfl_down(s2, o);
    if (lane == 0) red[wid] = s2;
    __syncthreads();
    float var = (red[0] + red[1] + red[2] + red[3]) * (1.f / C_);

    float out = dv * rsqrtf(var + 1e-5f) * g[t] + bta[t];
    x[idx]   = out;
    xbf[idx] = __float2bfloat16(out);
}

// ---------- driver ----------
extern "C" void kernel_launch(void* const* d_in, const int* in_sizes, int n_in,
                              void* d_out, int out_size, void* d_ws, size_t ws_size,
                              hipStream_t stream)
{
    const float* src_[4] = {(const float*)d_in[0], (const float*)d_in[2],
                            (const float*)d_in[4], (const float*)d_in[6]};
    const float* pos_[4] = {(const float*)d_in[1], (const float*)d_in[3],
                            (const float*)d_in[5], (const float*)d_in[7]};
    const float* lev   = (const float*)d_in[8];
    const float* Woff  = (const float*)d_in[9];
    const float* boff  = (const float*)d_in[10];
    const float* Wattn = (const float*)d_in[11];
    const float* battn = (const float*)d_in[12];
    const float* Wval  = (const float*)d_in[13];
    const float* bval  = (const float*)d_in[14];
    const float* Wout  = (const float*)d_in[15];
    const float* bout  = (const float*)d_in[16];
    const float* g1    = (const float*)d_in[17];
    const float* b1    = (const float*)d_in[18];
    const float* Wff1  = (const float*)d_in[19];
    const float* bff1  = (const float*)d_in[20];
    const float* Wff2  = (const float*)d_in[21];
    const float* bff2  = (const float*)d_in[22];
    const float* g2    = (const float*)d_in[23];
    const float* b2    = (const float*)d_in[24];

    float* x = (float*)d_out;                       // persistent hidden state (fp32)
    size_t MC = (size_t)M_ * C_;                    // 11,141,120

    __hip_bfloat16* pos_bf = (__hip_bfloat16*)d_ws;
    __hip_bfloat16* q_bf   = pos_bf + MC;           // q; later sampled output
    __hip_bfloat16* x_bf   = q_bf + MC;
    __hip_bfloat16* val_bf = x_bf + MC;
    __hip_bfloat16* ffh_bf = val_bf + MC;           // Mc*1024 == MC elems
    float* offb = (float*)(ffh_bf + MC);            // off -> out2 -> fftmp
    float* attb = offb + MC;                        // [M,128]
    __hip_bfloat16* wbf = (__hip_bfloat16*)(attb + (size_t)M_ * 128);

    __hip_bfloat16* wofft  = wbf;                       // 6*256*256
    __hip_bfloat16* wattnt = wofft  + 6 * 65536;        // 6*128*256
    __hip_bfloat16* wvalt  = wattnt + 6 * 32768;
    __hip_bfloat16* woutt  = wvalt  + 6 * 65536;
    __hip_bfloat16* wff1t  = woutt  + 6 * 65536;        // 6*1024*256
    __hip_bfloat16* wff2t  = wff1t  + 6 * 262144;       // 6*256*1024

    dim3 blk(256);
    dim3 tblk(32, 8);

    // weight transpose+cvt (runs in graph; ~10us total)
    k_wt<<<dim3(8, 8, 6),  tblk, 0, stream>>>(Woff,  wofft,  256, 256);
    k_wt<<<dim3(4, 8, 6),  tblk, 0, stream>>>(Wattn, wattnt, 256, 128);
    k_wt<<<dim3(8, 8, 6),  tblk, 0, stream>>>(Wval,  wvalt,  256, 256);
    k_wt<<<dim3(8, 8, 6),  tblk, 0, stream>>>(Wout,  woutt,  256, 256);
    k_wt<<<dim3(32, 8, 6), tblk, 0, stream>>>(Wff1,  wff1t,  256, 1024);
    k_wt<<<dim3(8, 32, 6), tblk, 0, stream>>>(Wff2,  wff2t,  1024, 256);

    int nElem = M_ * C_;
    k_assemble<<<(nElem + 255) / 256, blk, 0, stream>>>(
        src_[0], src_[1], src_[2], src_[3],
        pos_[0], pos_[1], pos_[2], pos_[3], lev, x, x_bf, pos_bf);

    int n8 = nElem / 8;

    for (int l = 0; l < 6; l++) {
        // q = bf16(x + pos)
        k_addq<<<(n8 + 255) / 256, blk, 0, stream>>>(
            (const float4*)x, (const u16x8*)pos_bf, (u16x8*)q_bf, n8);

        // off = q @ Woff + boff  [M,256] f32
        k_gemm_mfma<false, false><<<dim3(M_ / 128, 2), blk, 0, stream>>>(
            q_bf, wofft + (size_t)l * 65536, boff + l * 256, offb, M_, 256, C_);

        // attn logits  [M,128] f32
        k_gemm_mfma<false, false><<<dim3(M_ / 128, 1), blk, 0, stream>>>(
            q_bf, wattnt + (size_t)l * 32768, battn + l * 128, attb, M_, 128, C_);

        k_softmax16<<<(M_ * NH_ + 255) / 256, blk, 0, stream>>>(attb, M_ * NH_);

        // val = x @ Wval + bval  [M,256] bf16
        k_gemm_mfma<false, true><<<dim3(M_ / 128, 2), blk, 0, stream>>>(
            x_bf, wvalt + (size_t)l * 65536, bval + l * 256, val_bf, M_, 256, C_);

        // deformable sampling -> q_bf (q dead after the two GEMMs above)
        k_sample<<<M_, blk, 0, stream>>>(val_bf, offb, attb, q_bf);

        // out2 = sampled @ Wout + bout -> offb (f32)
        k_gemm_mfma<false, false><<<dim3(M_ / 128, 2), blk, 0, stream>>>(
            q_bf, woutt + (size_t)l * 65536, bout + l * 256, offb, M_, 256, C_);

        // x = LN(x + out2); refresh x_bf
        k_addln<<<M_, blk, 0, stream>>>(x, offb, g1 + l * 256, b1 + l * 256, x_bf);

        // FF in 4 row-chunks: ffh = relu(x@Wff1+b) bf16; fftmp = ffh@Wff2+b f32
        for (int ch = 0; ch < 4; ch++) {
            const __hip_bfloat16* xa = x_bf + (size_t)ch * Mc_ * C_;
            k_gemm_mfma<true, true><<<dim3(Mc_ / 128, 8), blk, 0, stream>>>(
                xa, wff1t + (size_t)l * 262144, bff1 + l * DFF_, ffh_bf, Mc_, DFF_, C_);
            k_gemm_mfma<false, false><<<dim3(Mc_ / 128, 2), blk, 0, stream>>>(
                ffh_bf, wff2t + (size_t)l * 262144, bff2 + l * C_,
                offb + (size_t)ch * Mc_ * C_, Mc_, 256, DFF_);
        }

        // x = LN(x + ff); refresh x_bf
        k_addln<<<M_, blk, 0, stream>>>(x, offb, g2 + l * 256, b2 + l * 256, x_bf);
    }
}

// Round 3
// 2476.374 us; speedup vs baseline: 3.4061x; 1.5804x over previous
//
#include <hip/hip_runtime.h>
#include <hip/hip_bf16.h>
#include <math.h>

namespace {
constexpr int B_   = 2;
constexpr int C_   = 256;
constexpr int NH_  = 8;
constexpr int DH_  = 32;
constexpr int NP_  = 4;
constexpr int DFF_ = 1024;
constexpr int LQ_  = 21760;
constexpr int M_   = B_ * LQ_;     // 43520
constexpr int Mc_  = M_ / 4;       // 10880 FF chunk rows
}

typedef __bf16  bf16x8 __attribute__((ext_vector_type(8)));
typedef short   s16x8  __attribute__((ext_vector_type(8)));
typedef unsigned short u16x8 __attribute__((ext_vector_type(8)));
typedef float   f32x4  __attribute__((ext_vector_type(4)));

static __device__ __forceinline__ unsigned short f2bf(float f) {
    return __builtin_bit_cast(unsigned short, __float2bfloat16(f));
}
static __device__ __forceinline__ float bf2f(unsigned short u) {
    return __bfloat162float(__builtin_bit_cast(__hip_bfloat16, u));
}

// ---------- weight transpose + cvt: in [L][K][N] f32 -> out [L][N][K] bf16 ----------
__global__ void k_wt(const float* __restrict__ in, __hip_bfloat16* __restrict__ out,
                     int K, int N)
{
    __shared__ float tile[32][33];
    int n0 = blockIdx.x * 32, k0 = blockIdx.y * 32;
    const float* inl = in + (size_t)blockIdx.z * K * N;
    __hip_bfloat16* outl = out + (size_t)blockIdx.z * K * N;
    for (int i = threadIdx.y; i < 32; i += 8)
        tile[i][threadIdx.x] = inl[(size_t)(k0 + i) * N + n0 + threadIdx.x];
    __syncthreads();
    for (int i = threadIdx.y; i < 32; i += 8)
        outl[(size_t)(n0 + i) * K + k0 + threadIdx.x] = __float2bfloat16(tile[threadIdx.x][i]);
}

// ---------- assemble: src/pos [B,C,H,W] -> [B,LQ,C]; pos += level_embed ----------
__global__ void k_assemble(const float* __restrict__ s0, const float* __restrict__ s1,
                           const float* __restrict__ s2, const float* __restrict__ s3,
                           const float* __restrict__ p0, const float* __restrict__ p1,
                           const float* __restrict__ p2, const float* __restrict__ p3,
                           const float* __restrict__ lev,
                           float* __restrict__ xout, __hip_bfloat16* __restrict__ xbf,
                           __hip_bfloat16* __restrict__ posbf)
{
    int i = blockIdx.x * blockDim.x + threadIdx.x;
    if (i >= B_ * LQ_ * C_) return;
    int c = i & (C_ - 1);
    int s = (i / C_) % LQ_;
    int b = i / (C_ * LQ_);
    const float *sp, *pp;
    int lv, off, HW;
    if (s < 16384)      { lv = 0; off = s;         HW = 16384; sp = s0; pp = p0; }
    else if (s < 20480) { lv = 1; off = s - 16384; HW = 4096;  sp = s1; pp = p1; }
    else if (s < 21504) { lv = 2; off = s - 20480; HW = 1024;  sp = s2; pp = p2; }
    else                { lv = 3; off = s - 21504; HW = 256;   sp = s3; pp = p3; }
    size_t si = ((size_t)(b * C_ + c)) * HW + off;
    float v = sp[si];
    xout[i]  = v;
    xbf[i]   = __float2bfloat16(v);
    posbf[i] = __float2bfloat16(pp[si] + lev[lv * C_ + c]);
}

// ---------- q_bf = bf16(x + pos_bf), 8 elems/thread ----------
__global__ void k_addq(const float4* __restrict__ x, const u16x8* __restrict__ pos,
                       u16x8* __restrict__ q, int n8)
{
    int i = blockIdx.x * blockDim.x + threadIdx.x;
    if (i >= n8) return;
    float4 a = x[2 * i], b = x[2 * i + 1];
    u16x8 p = pos[i];
    float va[8] = {a.x, a.y, a.z, a.w, b.x, b.y, b.z, b.w};
    u16x8 o;
#pragma unroll
    for (int j = 0; j < 8; j++)
        o[j] = f2bf(va[j] + bf2f(p[j]));
    q[i] = o;
}

// ---------- bf16 MFMA GEMM: out = A[M,K] @ W^T[N,K]^T + bias ----------
template<bool RELU, bool BF16OUT>
__global__ __launch_bounds__(256) void k_gemm_mfma(
    const __hip_bfloat16* __restrict__ A,    // [M,K]
    const __hip_bfloat16* __restrict__ Wt,   // [N,K]
    const float* __restrict__ bias,          // [N]
    void* __restrict__ Co,                   // [M,N] f32 or bf16
    int M, int N, int K)
{
    __shared__ char As[128 * 128];   // 128 rows x 128 bytes (64 bf16)
    __shared__ char Bs[128 * 128];
    int t = threadIdx.x, w = t >> 6, lane = t & 63;
    int m0 = blockIdx.x * 128, n0 = blockIdx.y * 128;
    int wm = w >> 1, wn = w & 1;

    f32x4 acc[4][4] = {};

    int rowoff  = lane >> 3;                                  // 0..7
    int colswz  = ((lane & 7) ^ (lane >> 3)) << 3;            // elements

    for (int kt = 0; kt < K; kt += 64) {
#pragma unroll
        for (int j = 0; j < 4; j++) {
            int rowbase = w * 32 + j * 8;
            const __hip_bfloat16* srcA = A  + (size_t)(m0 + rowbase + rowoff) * K + kt + colswz;
            const __hip_bfloat16* srcB = Wt + (size_t)(n0 + rowbase + rowoff) * K + kt + colswz;
            __builtin_amdgcn_global_load_lds(
                (const __attribute__((address_space(1))) void*)srcA,
                (__attribute__((address_space(3))) void*)(As + rowbase * 128), 16, 0, 0);
            __builtin_amdgcn_global_load_lds(
                (const __attribute__((address_space(1))) void*)srcB,
                (__attribute__((address_space(3))) void*)(Bs + rowbase * 128), 16, 0, 0);
        }
        __syncthreads();
#pragma unroll
        for (int k0 = 0; k0 < 64; k0 += 32) {
            int kb = k0 * 2 + (lane >> 4) * 16;
            bf16x8 af[4], bfr[4];
#pragma unroll
            for (int mi = 0; mi < 4; mi++) {
                int r = wm * 64 + mi * 16 + (lane & 15);
                s16x8 raw = *(const s16x8*)(As + r * 128 + (kb ^ ((r & 7) << 4)));
                af[mi] = __builtin_bit_cast(bf16x8, raw);
            }
#pragma unroll
            for (int ni = 0; ni < 4; ni++) {
                int r = wn * 64 + ni * 16 + (lane & 15);
                s16x8 raw = *(const s16x8*)(Bs + r * 128 + (kb ^ ((r & 7) << 4)));
                bfr[ni] = __builtin_bit_cast(bf16x8, raw);
            }
#pragma unroll
            for (int mi = 0; mi < 4; mi++)
#pragma unroll
                for (int ni = 0; ni < 4; ni++)
                    acc[mi][ni] = __builtin_amdgcn_mfma_f32_16x16x32_bf16(
                        af[mi], bfr[ni], acc[mi][ni], 0, 0, 0);
        }
        __syncthreads();
    }

#pragma unroll
    for (int ni = 0; ni < 4; ni++) {
        int col = n0 + wn * 64 + ni * 16 + (lane & 15);
        float bb = bias[col];
#pragma unroll
        for (int mi = 0; mi < 4; mi++) {
            int row = m0 + wm * 64 + mi * 16 + ((lane >> 4) << 2);
#pragma unroll
            for (int r = 0; r < 4; r++) {
                float v = acc[mi][ni][r] + bb;
                if (RELU) v = fmaxf(v, 0.f);
                if (BF16OUT)
                    ((__hip_bfloat16*)Co)[(size_t)(row + r) * N + col] = __float2bfloat16(v);
                else
                    ((float*)Co)[(size_t)(row + r) * N + col] = v;
            }
        }
    }
}

// ---------- deformable sampling v2: fused softmax + precomputed weights ----------
// 2 queries per block. Phase 1: 256 thr = 2x128 points (softmax + bilinear setup).
// Phase 2: thread = (query, head, d-pair); gathers with premultiplied weights.
__global__ __launch_bounds__(256) void k_sample2(const __hip_bfloat16* __restrict__ val,
                                                 const float* __restrict__ off,
                                                 const float* __restrict__ logits,
                                                 __hip_bfloat16* __restrict__ out)
{
    __shared__ int   sIdx[16 * 65];   // [2*8 head-groups][16 pts * 4 corners + pad]
    __shared__ float sW[16 * 65];

    int t  = threadIdx.x;
    int qb = blockIdx.x;              // 2 queries per block

    // ---- phase 1 ----
    {
        int qi = t >> 7;              // local query
        int pt = t & 127;             // point id: h*16 + lv*4 + p
        int bs = qb * 2 + qi;
        int b  = bs / LQ_;
        int s  = bs % LQ_;
        int h  = pt >> 4, lv = (pt >> 2) & 3;

        // fused softmax over the 16 points of this head (16-lane shfl groups)
        float lg = logits[(size_t)bs * 128 + pt];
        float mx = lg;
#pragma unroll
        for (int m = 1; m < 16; m <<= 1) mx = fmaxf(mx, __shfl_xor(mx, m));
        float ex = __expf(lg - mx);
        float sm = ex;
#pragma unroll
        for (int m = 1; m < 16; m <<= 1) sm += __shfl_xor(sm, m);
        float aw = ex / sm;

        // query's own reference point
        int p0, Wq;
        if (s < 16384)      { p0 = s;         Wq = 128; }
        else if (s < 20480) { p0 = s - 16384; Wq = 64;  }
        else if (s < 21504) { p0 = s - 20480; Wq = 32;  }
        else                { p0 = s - 21504; Wq = 16;  }
        float invWq = 1.f / (float)Wq;
        float refx = ((p0 % Wq) + 0.5f) * invWq;
        float refy = ((p0 / Wq) + 0.5f) * invWq;

        // sampled level geometry
        int W  = 128 >> lv;
        int S0 = (65536 - (65536 >> (2 * lv))) / 3;   // 0,16384,20480,21504
        float fW = (float)W;

        float2 o2 = ((const float2*)(off + (size_t)bs * 256))[pt];
        float xx = refx * fW + o2.x - 0.5f;
        float yy = refy * fW + o2.y - 0.5f;
        float x0f = floorf(xx), y0f = floorf(yy);
        float wx = xx - x0f, wy = yy - y0f;
        int x0 = (int)x0f, y0 = (int)y0f;
        int x1 = x0 + 1, y1 = y0 + 1;
        bool vx0 = (x0 >= 0) & (x0 < W), vx1 = (x1 >= 0) & (x1 < W);
        bool vy0 = (y0 >= 0) & (y0 < W), vy1 = (y1 >= 0) & (y1 < W);
        int cx0 = min(max(x0, 0), W - 1), cx1 = min(max(x1, 0), W - 1);
        int cy0 = min(max(y0, 0), W - 1), cy1 = min(max(y1, 0), W - 1);

        int rowbase = (b * LQ_ + S0) * C_ + h * DH_;      // element offset
        int g = t >> 4;                                    // qi*8 + h
        int slot = g * 65 + (pt & 15) * 4;
        sIdx[slot + 0] = (rowbase + (cy0 * W + cx0) * C_) * 2;   // byte offsets
        sIdx[slot + 1] = (rowbase + (cy0 * W + cx1) * C_) * 2;
        sIdx[slot + 2] = (rowbase + (cy1 * W + cx0) * C_) * 2;
        sIdx[slot + 3] = (rowbase + (cy1 * W + cx1) * C_) * 2;
        sW[slot + 0] = aw * (1.f - wx) * (1.f - wy) * ((vx0 & vy0) ? 1.f : 0.f);
        sW[slot + 1] = aw * wx * (1.f - wy) * ((vx1 & vy0) ? 1.f : 0.f);
        sW[slot + 2] = aw * (1.f - wx) * wy * ((vx0 & vy1) ? 1.f : 0.f);
        sW[slot + 3] = aw * wx * wy * ((vx1 & vy1) ? 1.f : 0.f);
    }
    __syncthreads();

    // ---- phase 2 ----
    {
        int qi = t >> 7;
        int r  = t & 127;
        int h  = r >> 4;
        int dp = r & 15;              // d-pair: d = dp*2, dp*2+1
        int bs = qb * 2 + qi;
        int g  = (qi << 3) + h;
        int dbyte = dp * 4;

        const char* vbase = (const char*)val;
        float acc0 = 0.f, acc1 = 0.f;
#pragma unroll
        for (int j = 0; j < 16; j++) {
            int base = g * 65 + j * 4;
#pragma unroll
            for (int k = 0; k < 4; k++) {
                int   ib = sIdx[base + k] + dbyte;
                float w  = sW[base + k];
                unsigned u = *(const unsigned*)(vbase + ib);
                float lo = __builtin_bit_cast(float, u << 16);
                float hi = __builtin_bit_cast(float, u & 0xffff0000u);
                acc0 = fmaf(w, lo, acc0);
                acc1 = fmaf(w, hi, acc1);
            }
        }
        unsigned o = (unsigned)f2bf(acc0) | ((unsigned)f2bf(acc1) << 16);
        *(unsigned*)((char*)out + (size_t)bs * 512 + h * 64 + dp * 4) = o;
    }
}

// ---------- x = LN(x + res) * g + b; also write bf16 copy ----------
__global__ __launch_bounds__(256) void k_addln(float* __restrict__ x,
                                               const float* __restrict__ res,
                                               const float* __restrict__ g,
                                               const float* __restrict__ bta,
                                               __hip_bfloat16* __restrict__ xbf)
{
    int r = blockIdx.x;
    int t = threadIdx.x;
    size_t idx = (size_t)r * C_ + t;
    float v = x[idx] + res[idx];

    __shared__ float red[4];
    int lane = t & 63, wid = t >> 6;

    float s = v;
#pragma unroll
    for (int o = 32; o > 0; o >>= 1) s += __shfl_down(s, o);
    if (lane == 0) red[wid] = s;
    __syncthreads();
    float mu = (red[0] + red[1] + red[2] + red[3]) * (1.f / C_);
    __syncthreads();

    float dv = v - mu;
    float s2 = dv * dv;
#pragma unroll
    for (int o = 32; o > 0; o >>= 1) s2 += __shfl_down(s2, o);
    if (lane == 0) red[wid] = s2;
    __syncthreads();
    float var = (red[0] + red[1] + red[2] + red[3]) * (1.f / C_);

    float out = dv * rsqrtf(var + 1e-5f) * g[t] + bta[t];
    x[idx]   = out;
    xbf[idx] = __float2bfloat16(out);
}

// ---------- driver ----------
extern "C" void kernel_launch(void* const* d_in, const int* in_sizes, int n_in,
                              void* d_out, int out_size, void* d_ws, size_t ws_size,
                              hipStream_t stream)
{
    const float* src_[4] = {(const float*)d_in[0], (const float*)d_in[2],
                            (const float*)d_in[4], (const float*)d_in[6]};
    const float* pos_[4] = {(const float*)d_in[1], (const float*)d_in[3],
                            (const float*)d_in[5], (const float*)d_in[7]};
    const float* lev   = (const float*)d_in[8];
    const float* Woff  = (const float*)d_in[9];
    const float* boff  = (const float*)d_in[10];
    const float* Wattn = (const float*)d_in[11];
    const float* battn = (const float*)d_in[12];
    const float* Wval  = (const float*)d_in[13];
    const float* bval  = (const float*)d_in[14];
    const float* Wout  = (const float*)d_in[15];
    const float* bout  = (const float*)d_in[16];
    const float* g1    = (const float*)d_in[17];
    const float* b1    = (const float*)d_in[18];
    const float* Wff1  = (const float*)d_in[19];
    const float* bff1  = (const float*)d_in[20];
    const float* Wff2  = (const float*)d_in[21];
    const float* bff2  = (const float*)d_in[22];
    const float* g2    = (const float*)d_in[23];
    const float* b2    = (const float*)d_in[24];

    float* x = (float*)d_out;                       // persistent hidden state (fp32)
    size_t MC = (size_t)M_ * C_;

    __hip_bfloat16* pos_bf = (__hip_bfloat16*)d_ws;
    __hip_bfloat16* q_bf   = pos_bf + MC;           // q; later sampled output
    __hip_bfloat16* x_bf   = q_bf + MC;
    __hip_bfloat16* val_bf = x_bf + MC;
    __hip_bfloat16* ffh_bf = val_bf + MC;           // Mc*1024 == MC elems
    float* offb = (float*)(ffh_bf + MC);            // off -> out2 -> fftmp
    float* attb = offb + MC;                        // [M,128] logits
    __hip_bfloat16* wbf = (__hip_bfloat16*)(attb + (size_t)M_ * 128);

    __hip_bfloat16* wofft  = wbf;
    __hip_bfloat16* wattnt = wofft  + 6 * 65536;
    __hip_bfloat16* wvalt  = wattnt + 6 * 32768;
    __hip_bfloat16* woutt  = wvalt  + 6 * 65536;
    __hip_bfloat16* wff1t  = woutt  + 6 * 65536;
    __hip_bfloat16* wff2t  = wff1t  + 6 * 262144;

    dim3 blk(256);
    dim3 tblk(32, 8);

    k_wt<<<dim3(8, 8, 6),  tblk, 0, stream>>>(Woff,  wofft,  256, 256);
    k_wt<<<dim3(4, 8, 6),  tblk, 0, stream>>>(Wattn, wattnt, 256, 128);
    k_wt<<<dim3(8, 8, 6),  tblk, 0, stream>>>(Wval,  wvalt,  256, 256);
    k_wt<<<dim3(8, 8, 6),  tblk, 0, stream>>>(Wout,  woutt,  256, 256);
    k_wt<<<dim3(32, 8, 6), tblk, 0, stream>>>(Wff1,  wff1t,  256, 1024);
    k_wt<<<dim3(8, 32, 6), tblk, 0, stream>>>(Wff2,  wff2t,  1024, 256);

    int nElem = M_ * C_;
    k_assemble<<<(nElem + 255) / 256, blk, 0, stream>>>(
        src_[0], src_[1], src_[2], src_[3],
        pos_[0], pos_[1], pos_[2], pos_[3], lev, x, x_bf, pos_bf);

    int n8 = nElem / 8;

    for (int l = 0; l < 6; l++) {
        // q = bf16(x + pos)
        k_addq<<<(n8 + 255) / 256, blk, 0, stream>>>(
            (const float4*)x, (const u16x8*)pos_bf, (u16x8*)q_bf, n8);

        // off = q @ Woff + boff  [M,256] f32
        k_gemm_mfma<false, false><<<dim3(M_ / 128, 2), blk, 0, stream>>>(
            q_bf, wofft + (size_t)l * 65536, boff + l * 256, offb, M_, 256, C_);

        // attn logits  [M,128] f32 (softmax fused into k_sample2)
        k_gemm_mfma<false, false><<<dim3(M_ / 128, 1), blk, 0, stream>>>(
            q_bf, wattnt + (size_t)l * 32768, battn + l * 128, attb, M_, 128, C_);

        // val = x @ Wval + bval  [M,256] bf16
        k_gemm_mfma<false, true><<<dim3(M_ / 128, 2), blk, 0, stream>>>(
            x_bf, wvalt + (size_t)l * 65536, bval + l * 256, val_bf, M_, 256, C_);

        // deformable sampling (softmax fused) -> q_bf
        k_sample2<<<M_ / 2, blk, 0, stream>>>(val_bf, offb, attb, q_bf);

        // out2 = sampled @ Wout + bout -> offb (f32)
        k_gemm_mfma<false, false><<<dim3(M_ / 128, 2), blk, 0, stream>>>(
            q_bf, woutt + (size_t)l * 65536, bout + l * 256, offb, M_, 256, C_);

        // x = LN(x + out2); refresh x_bf
        k_addln<<<M_, blk, 0, stream>>>(x, offb, g1 + l * 256, b1 + l * 256, x_bf);

        // FF in 4 row-chunks
        for (int ch = 0; ch < 4; ch++) {
            const __hip_bfloat16* xa = x_bf + (size_t)ch * Mc_ * C_;
            k_gemm_mfma<true, true><<<dim3(Mc_ / 128, 8), blk, 0, stream>>>(
                xa, wff1t + (size_t)l * 262144, bff1 + l * DFF_, ffh_bf, Mc_, DFF_, C_);
            k_gemm_mfma<false, false><<<dim3(Mc_ / 128, 2), blk, 0, stream>>>(
                ffh_bf, wff2t + (size_t)l * 262144, bff2 + l * C_,
                offb + (size_t)ch * Mc_ * C_, Mc_, 256, DFF_);
        }

        // x = LN(x + ff); refresh x_bf
        k_addln<<<M_, blk, 0, stream>>>(x, offb, g2 + l * 256, b2 + l * 256, x_bf);
    }
}